// Round 15
// baseline (1639.970 us; speedup 1.0000x reference)
//
#include <hip/hip_runtime.h>
#include <stdint.h>

#define BN_ 2
#define NPT 16384
#define MPT 8192
#define NROI 128
#define KP 2048

typedef unsigned long long u64;
typedef unsigned u32;
typedef float v2f __attribute__((ext_vector_type(2)));

// ---- workspace layout (float offsets) ----
#define FEATS_LEN (4096*352)
#define CNTR_OFF  (FEATS_LEN)
#define CNTC_OFF  (CNTR_OFF + 4096)
#define FRAW_OFF  (CNTC_OFF + 4096)
#define FRAW_LEN  (BN_*NPT*32)
#define GC3_OFF   (FRAW_OFF + FRAW_LEN)
#define GC3_LEN   (BN_*MPT*64)
#define FLAGS_F_OFF (GC3_OFF + GC3_LEN)      // flags (bytes) at this float offset
#define PX_OFF    (FLAGS_F_OFF + (BN_*NPT)/4) // SoA compacted coords (fallback)
#define PY_OFF    (PX_OFF + BN_*NPT)
#define PZ_OFF    (PY_OFF + BN_*NPT)
#define SFT_OFF   (PZ_OFF + BN_*NPT)         // channel-last BEV (optional, ws-size gated)
#define NPOS      (188*188)                  // 35344
#define SFT_LEN   (BN_*NPOS*256)
#define OUT_KP_OFF (4096*128)                // keypoints region inside d_out

// fused-dispatch block roles for k_fps
#define FPS_BLOCKS  2
#define GC3_BLOCKS  2048                      // 8 rows x 512thr each
#define ZERO_BLOCKS 177                       // (FEATS_LEN+8192)/4 f4 = 362496 = 177*512*4
#define FRAW_BLOCKS 1024                      // BN_*NPT*32 = 1048576 = 1024*512*2
#define PTILES      553                       // ceil(35344/64)
#define SFT_BLOCKS  (BN_*4*PTILES)            // 4 k-tiles x 553 pos-tiles per batch
#define BASE_BLOCKS (FPS_BLOCKS + GC3_BLOCKS + ZERO_BLOCKS + FRAW_BLOCKS)
#define TOTAL_BLOCKS (BASE_BLOCKS + SFT_BLOCKS)

// ---------------- helpers ----------------
template <int CTRL>
__device__ __forceinline__ u32 dppmov(u32 v) {
    return (u32)__builtin_amdgcn_update_dpp((int)v, (int)v, CTRL, 0xF, 0xF, false);
}
// Wave64 u32 max via DPP; result broadcast via readlane(63).
__device__ __forceinline__ u32 wave_umax32_dpp(u32 v) {
#define STG(C) { u32 o = dppmov<C>(v); v = (o > v) ? o : v; }
    STG(0x111) STG(0x112) STG(0x114) STG(0x118) STG(0x142) STG(0x143)
#undef STG
    return (u32)__builtin_amdgcn_readlane((int)v, 63);
}

// packed f32 ops (VOP3P) — exact IEEE per half, no contraction possible.
__device__ __forceinline__ v2f pk_add(v2f a, v2f b) {
    v2f r; asm("v_pk_add_f32 %0, %1, %2" : "=v"(r) : "v"(a), "v"(b)); return r;
}
__device__ __forceinline__ v2f pk_mul(v2f a, v2f b) {
    v2f r; asm("v_pk_mul_f32 %0, %1, %2" : "=v"(r) : "v"(a), "v"(b)); return r;
}

// ---------------- K1: ROI validity flags (pure — fraw moved to fused dispatch) ---
__global__ void k_flags(const float* __restrict__ pts, const float* __restrict__ bbox,
                        unsigned char* __restrict__ flags) {
#pragma clang fp contract(off)
    __shared__ float rx[NROI], ry[NROI], rz[NROI], rt[NROI];
    int b = blockIdx.x >> 6;
    int t = threadIdx.x;
    if (t < NROI) {
        const float* rr = bbox + (size_t)(b * NROI + t) * 7;
        rx[t] = rr[0]; ry[t] = rr[1]; rz[t] = rr[2];
        float hx = rr[3] * 0.5f, hy = rr[4] * 0.5f, hz = rr[5] * 0.5f;
        rt[t] = sqrtf(((hx * hx) + (hy * hy)) + (hz * hz)) + 2.4f;
    }
    __syncthreads();
    int p = (blockIdx.x & 63) * 256 + t;
    int n = b * NPT + p;
    const float* pr = pts + (size_t)n * 5;
    float x = pr[0], y = pr[1], z = pr[2];
    float mind = 3.4e38f, th = 0.f;
    for (int r = 0; r < NROI; ++r) {
        float dx = x - rx[r], dy = y - ry[r], dz = z - rz[r];
        float ds = sqrtf(((dx * dx) + (dy * dy)) + (dz * dz));
        if (ds < mind) { mind = ds; th = rt[r]; }   // strict < : first-min == np.argmin
    }
    flags[n] = (mind < th) ? 1 : 0;
}

// ---------------- FPS inner loop, LDS-coords variant (R12/R14, verified 1372us) --
// Compacted coords live in LDS (cbuf, float4). Winner fetch is ONE broadcast
// ds_read_b128. Tournament via triple-buffered single LDS slot + ds_max_u64
// from the SINGLE uniform lane (lane==0 after ballot/ctz/readlane — R13 proved
// the divergent-predicate form is 5.5x slower). Key = d_bits<<14 | 0x3FFF-gid:
// exact first-index tie-break (d >= +0.0; pads d=+0.0 lose since pad gid >= V).
template <int NS>
__device__ __forceinline__ void fps_loop_l(
    int t, int lane, int w, int V,
    const float4* cbuf,               // LDS compacted coords
    u64* rbuf,                        // LDS, 3 rotating winner slots
    float* kbuf,                      // LDS, KP*3
    float* __restrict__ kout) {
#pragma clang fp contract(off)
    constexpr int NP = NS / 2;
    v2f px[NP], py[NP], pz[NP];
    float d[NS];
    int base = t * NS;                // even (NS even)
#pragma unroll
    for (int m = 0; m < NP; ++m) {
        int id0 = base + 2 * m;
        float4 a = cbuf[id0];
        float4 c = cbuf[id0 + 1];
        bool in0 = id0 < V, in1 = (id0 + 1) < V;
        px[m].x = in0 ? a.x : 1e18f;  px[m].y = in1 ? c.x : 1e18f;
        py[m].x = in0 ? a.y : 1e18f;  py[m].y = in1 ? c.y : 1e18f;
        pz[m].x = in0 ? a.z : 1e18f;  pz[m].y = in1 ? c.z : 1e18f;
        d[2 * m]     = in0 ? 1e10f : 0.0f;   // pad: +0.0 -> loses all ties via gid
        d[2 * m + 1] = in1 ? 1e10f : 0.0f;
    }

    // prime: argmax over initial d (ties -> lowest j, then lowest lane)
    float bestD = -3.4e38f; int bestJ = 0;
#pragma unroll
    for (int j = 0; j < NS; ++j)
        if (d[j] > bestD) { bestD = d[j]; bestJ = j; }
    u32 gid = (u32)(base + bestJ);
    u32 ord = __float_as_uint(bestD);
    u32 maxOrd = wave_umax32_dpp(ord);
    u64 eq = __ballot(ord == maxOrd);
    int L = __builtin_ctzll(eq);
    u32 winGid = (u32)__builtin_amdgcn_readlane((int)gid, L);
    if (lane == 0)
        atomicMax((unsigned long long*)&rbuf[0],
                  ((u64)maxOrd << 14) | (u64)(0x3FFFu - winGid));
    __syncthreads();

    int rd = 0, wr = 1, zr = 2;
    for (int k = 0; k < KP; ++k) {
        // block winner: ONE uniform u64 read, then ONE broadcast b128 read
        u64 win = rbuf[rd];
        u32 wid = 0x3FFFu - ((u32)win & 0x3FFFu);
        float4 wq = cbuf[wid];        // uniform LDS broadcast, no conflict
        float wx = wq.x, wy = wq.y, wz = wq.z;
        if (t == 0) {
            kbuf[k * 3] = wx; kbuf[k * 3 + 1] = wy; kbuf[k * 3 + 2] = wz;
            rbuf[zr] = 0;     // re-zero the idle slot (read finished at k-1)
        }
        v2f wnx; wnx.x = -wx; wnx.y = -wx;
        v2f wny; wny.x = -wy; wny.y = -wy;
        v2f wnz; wnz.x = -wz; wnz.y = -wz;

        // update + sequential local argmax, packed-f32 core (exact: IEEE per
        // half; p + (-w) == p - w exactly)
        bestD = -3.4e38f; bestJ = 0;
#pragma unroll
        for (int m = 0; m < NP; ++m) {
            v2f dx = pk_add(px[m], wnx);
            v2f dy = pk_add(py[m], wny);
            v2f dz = pk_add(pz[m], wnz);
            v2f s  = pk_mul(dx, dx);
            v2f s2 = pk_mul(dy, dy);
            v2f s3 = pk_mul(dz, dz);
            s = pk_add(s, s2);
            s = pk_add(s, s3);
            float dn0 = fminf(d[2 * m], s.x);
            float dn1 = fminf(d[2 * m + 1], s.y);
            d[2 * m] = dn0; d[2 * m + 1] = dn1;
            if (dn0 > bestD) { bestD = dn0; bestJ = 2 * m; }
            if (dn1 > bestD) { bestD = dn1; bestJ = 2 * m + 1; }
        }
        gid = (u32)(base + bestJ);
        ord = __float_as_uint(bestD);
        maxOrd = wave_umax32_dpp(ord);
        eq = __ballot(ord == maxOrd);
        L = __builtin_ctzll(eq);
        winGid = (u32)__builtin_amdgcn_readlane((int)gid, L);
        if (lane == 0)
            atomicMax((unsigned long long*)&rbuf[wr],
                      ((u64)maxOrd << 14) | (u64)(0x3FFFu - winGid));
        __syncthreads();
        int tmp = rd; rd = wr; wr = zr; zr = tmp;
    }
    // flush keypoints LDS -> global (coalesced, once)
    for (int i = t; i < KP * 3; i += 512) kout[i] = kbuf[i];
}

// ---------------- FPS fallback (global SoA), V > 6144 ---------------------------
template <int NS>
__device__ __forceinline__ void fps_loop_g(
    int t, int lane, int w, int V,
    const float* __restrict__ pxg, const float* __restrict__ pyg,
    const float* __restrict__ pzg,
    u64* rbuf, float* kbuf, float* __restrict__ kout) {
#pragma clang fp contract(off)
    constexpr int NP = NS / 2;
    v2f px[NP], py[NP], pz[NP];
    float d[NS];
    int base = t * NS;
#pragma unroll
    for (int m = 0; m < NP; ++m) {
        int id0 = base + 2 * m;
        v2f qx = ((const v2f*)pxg)[base / 2 + m];
        v2f qy = ((const v2f*)pyg)[base / 2 + m];
        v2f qz = ((const v2f*)pzg)[base / 2 + m];
        bool in0 = id0 < V, in1 = (id0 + 1) < V;
        px[m].x = in0 ? qx.x : 1e18f;  px[m].y = in1 ? qx.y : 1e18f;
        py[m].x = in0 ? qy.x : 1e18f;  py[m].y = in1 ? qy.y : 1e18f;
        pz[m].x = in0 ? qz.x : 1e18f;  pz[m].y = in1 ? qz.y : 1e18f;
        d[2 * m]     = in0 ? 1e10f : 0.0f;
        d[2 * m + 1] = in1 ? 1e10f : 0.0f;
    }
    float bestD = -3.4e38f; int bestJ = 0;
#pragma unroll
    for (int j = 0; j < NS; ++j)
        if (d[j] > bestD) { bestD = d[j]; bestJ = j; }
    u32 gid = (u32)(base + bestJ);
    u32 ord = __float_as_uint(bestD);
    u32 maxOrd = wave_umax32_dpp(ord);
    u64 eq = __ballot(ord == maxOrd);
    int L = __builtin_ctzll(eq);
    u32 winGid = (u32)__builtin_amdgcn_readlane((int)gid, L);
    if (lane == 0)
        atomicMax((unsigned long long*)&rbuf[0],
                  ((u64)maxOrd << 14) | (u64)(0x3FFFu - winGid));
    __syncthreads();

    int rd = 0, wr = 1, zr = 2;
    for (int k = 0; k < KP; ++k) {
        u64 win = rbuf[rd];
        u32 wid = 0x3FFFu - ((u32)win & 0x3FFFu);
        float wx = pxg[wid], wy = pyg[wid], wz = pzg[wid];
        if (t == 0) {
            kbuf[k * 3] = wx; kbuf[k * 3 + 1] = wy; kbuf[k * 3 + 2] = wz;
            rbuf[zr] = 0;
        }
        v2f wnx; wnx.x = -wx; wnx.y = -wx;
        v2f wny; wny.x = -wy; wny.y = -wy;
        v2f wnz; wnz.x = -wz; wnz.y = -wz;
        bestD = -3.4e38f; bestJ = 0;
#pragma unroll
        for (int m = 0; m < NP; ++m) {
            v2f dx = pk_add(px[m], wnx);
            v2f dy = pk_add(py[m], wny);
            v2f dz = pk_add(pz[m], wnz);
            v2f s  = pk_mul(dx, dx);
            v2f s2 = pk_mul(dy, dy);
            v2f s3 = pk_mul(dz, dz);
            s = pk_add(s, s2);
            s = pk_add(s, s3);
            float dn0 = fminf(d[2 * m], s.x);
            float dn1 = fminf(d[2 * m + 1], s.y);
            d[2 * m] = dn0; d[2 * m + 1] = dn1;
            if (dn0 > bestD) { bestD = dn0; bestJ = 2 * m; }
            if (dn1 > bestD) { bestD = dn1; bestJ = 2 * m + 1; }
        }
        gid = (u32)(base + bestJ);
        ord = __float_as_uint(bestD);
        maxOrd = wave_umax32_dpp(ord);
        eq = __ballot(ord == maxOrd);
        L = __builtin_ctzll(eq);
        winGid = (u32)__builtin_amdgcn_readlane((int)gid, L);
        if (lane == 0)
            atomicMax((unsigned long long*)&rbuf[wr],
                      ((u64)maxOrd << 14) | (u64)(0x3FFFu - winGid));
        __syncthreads();
        int tmp = rd; rd = wr; wr = zr; zr = tmp;
    }
    for (int i = t; i < KP * 3; i += 512) kout[i] = kbuf[i];
}

// ---------------- K2: fused dispatch — FPS + gc3 + zeroing + fraw + sf transpose -
// LDS layout (122944 B): rbuf 24 | wtot 32 | kbuf 24576 | cbuf 98304.
// Helper roles (gc3/zero/fraw/sfT) run on the 254 idle CUs under the ~1.37ms
// FPS shadow; fraw moved here from k_flags (no dependency on flags) to shorten
// the serial prefix before FPS.
__global__ void __launch_bounds__(512, 2)
k_fps(const float* __restrict__ pts, const unsigned char* __restrict__ flags,
      float* __restrict__ pxw, float* __restrict__ pyw, float* __restrict__ pzw,
      float* __restrict__ kpOut,
      const float* __restrict__ conv3, const float* __restrict__ Wc,
      const float* __restrict__ bc, float* __restrict__ gc3,
      float* __restrict__ zbase,
      const float* __restrict__ Wr, const float* __restrict__ br,
      float* __restrict__ fraw,
      const float* __restrict__ sf, float* __restrict__ sfT) {
#pragma clang fp contract(off)
    __shared__ __align__(16) unsigned char smem[122944];
    int bid = blockIdx.x;
    int t = threadIdx.x;

    if (bid >= BASE_BLOCKS) {
        // ---- sf transpose: 64pos x 64k tile via LDS (conflict-free pad) ----
        int tb = bid - BASE_BLOCKS;            // 0..SFT_BLOCKS-1
        int pt = tb % PTILES;
        int rem = tb / PTILES;                 // 0..(BN_*4-1)
        int kt = rem & 3;
        int bb = rem >> 2;
        int pos0 = pt * 64;
        int k0 = kt * 64;
        float* lds = (float*)smem;             // [64][65]
        int g = t >> 6, l = t & 63;
        const float* src = sf + ((size_t)(bb * 256 + k0) * NPOS) + pos0;
#pragma unroll
        for (int i = 0; i < 8; ++i) {
            int kl = g + 8 * i;
            float v = (pos0 + l < NPOS) ? src[(size_t)kl * NPOS + l] : 0.f;
            lds[kl * 65 + l] = v;
        }
        __syncthreads();
        float* dst = sfT + (size_t)bb * NPOS * 256;
#pragma unroll
        for (int i = 0; i < 8; ++i) {
            int pl = g + 8 * i;
            int pos = pos0 + pl;
            if (pos < NPOS)
                dst[(size_t)pos * 256 + k0 + l] = lds[l * 65 + pl];
        }
        return;
    }
    if (bid >= FPS_BLOCKS + GC3_BLOCKS + ZERO_BLOCKS) {
        // ---- fraw MLP: relu(f3*W0[c] + f4*W1[c] + b[c]), 2 elems/thread ----
        int blkLocal = bid - FPS_BLOCKS - GC3_BLOCKS - ZERO_BLOCKS;
#pragma unroll
        for (int e = 0; e < 2; ++e) {
            int idx = blkLocal * 1024 + e * 512 + t;   // < BN_*NPT*32
            int c = idx & 31, n = idx >> 5;
            const float* pr = pts + (size_t)n * 5;
            float v = fmaf(pr[3], Wr[c], fmaf(pr[4], Wr[32 + c], br[c]));
            fraw[(size_t)n * 32 + c] = fmaxf(v, 0.f);
        }
        return;
    }
    if (bid >= FPS_BLOCKS + GC3_BLOCKS) {
        // ---- zero feats + counters: 4 float4 per thread, exact coverage ----
        float4* z4 = (float4*)zbase;
        int idx = (bid - FPS_BLOCKS - GC3_BLOCKS) * 512 + t;
        const int STRIDE = ZERO_BLOCKS * 512;
#pragma unroll
        for (int k = 0; k < 4; ++k)
            z4[idx + k * STRIDE] = make_float4(0.f, 0.f, 0.f, 0.f);
        return;
    }
    if (bid >= FPS_BLOCKS) {
        // ---- gc3 MLP: 8 rows per block, bit-identical to former k_gc3 ----
        float* w = (float*)smem;                       // 16KB
        float (*rf)[64] = (float(*)[64])(smem + 16384); // 2KB
        for (int i = t; i < 4096; i += 512) w[i] = Wc[i];
        int r = (bid - FPS_BLOCKS) * 8 + (t >> 6);
        int c = t & 63;
        rf[t >> 6][c] = conv3[(size_t)r * 67 + 3 + c];
        __syncthreads();
        float s = bc[c];
#pragma unroll 8
        for (int k = 0; k < 64; ++k) s = fmaf(rf[t >> 6][k], w[k * 64 + c], s);
        gc3[(size_t)r * 64 + c] = fmaxf(s, 0.f);
        return;
    }

    // ---- FPS path (blocks 0..1), 512 threads = 8 waves = 2 waves/SIMD ----
    u64* rbuf    = (u64*)smem;                         // 24 B (3 slots)
    int* wtot    = (int*)(smem + 32);                  // 32 B
    float* kbuf  = (float*)(smem + 64);                // 24576 B -> ends 24640
    float4* cbuf = (float4*)(smem + 24640);            // 98304 B -> ends 122944

    int b = bid;
    int lane = t & 63, w = t >> 6;
    int chunk = t * 32;   // 32 contiguous input points per thread
    const float* pbase = pts + (size_t)b * NPT * 5;
    const unsigned char* fbase = flags + b * NPT;

    if (t < 3) rbuf[t] = 0;   // zero winner slots (visible after barrier below)

    // pass 1: count valid in my chunk
    int cnt = 0;
    for (int j = 0; j < 32; ++j) cnt += fbase[chunk + j] ? 1 : 0;
    int incl = cnt;
#pragma unroll
    for (int off = 1; off < 64; off <<= 1) {
        int v = __shfl_up(incl, off, 64);
        if (lane >= off) incl += v;
    }
    if (lane == 63) wtot[w] = incl;
    __syncthreads();
    int waveBase = 0, V = 0;
    for (int i = 0; i < 8; ++i) { int wv = wtot[i]; V += wv; if (i < w) waveBase += wv; }
    int pos = waveBase + incl - cnt;

    float* kout = kpOut + (size_t)b * KP * 3;
    if (V == 0) {      // degenerate: reference picks index 0 every step
        if (t == 0)
            for (int k = 0; k < KP; ++k) {
                kout[k * 3] = pbase[0]; kout[k * 3 + 1] = pbase[1]; kout[k * 3 + 2] = pbase[2];
            }
        return;
    }

    if (V <= 6144) {
        // pass 2: stable scatter of compacted coords into LDS cbuf
        for (int j = 0; j < 32; ++j) {
            if (fbase[chunk + j]) {
                const float* pr = pbase + (size_t)(chunk + j) * 5;
                cbuf[pos] = make_float4(pr[0], pr[1], pr[2], 0.f);
                ++pos;
            }
        }
        __syncthreads();   // scatter + rbuf zeroing visible to block
        int jm = (V + 511) >> 9;
        if (jm <= 10)      fps_loop_l<10>(t, lane, w, V, cbuf, rbuf, kbuf, kout);
        else               fps_loop_l<12>(t, lane, w, V, cbuf, rbuf, kbuf, kout);
    } else {
        // fallback: scatter to global SoA ws
        float* pxg = pxw + (size_t)b * NPT;
        float* pyg = pyw + (size_t)b * NPT;
        float* pzg = pzw + (size_t)b * NPT;
        int pp = pos;
        for (int j = 0; j < 32; ++j) {
            if (fbase[chunk + j]) {
                const float* pr = pbase + (size_t)(chunk + j) * 5;
                pxg[pp] = pr[0]; pyg[pp] = pr[1]; pzg[pp] = pr[2];
                ++pp;
            }
        }
        __syncthreads();
        int jm = (V + 511) >> 9;
        if (jm <= 14)      fps_loop_g<14>(t, lane, w, V, pxg, pyg, pzg, rbuf, kbuf, kout);
        else if (jm <= 16) fps_loop_g<16>(t, lane, w, V, pxg, pyg, pzg, rbuf, kbuf, kout);
        else if (jm <= 24) fps_loop_g<24>(t, lane, w, V, pxg, pyg, pzg, rbuf, kbuf, kout);
        else               fps_loop_g<32>(t, lane, w, V, pxg, pyg, pzg, rbuf, kbuf, kout);
    }
}

// ---------------- K5+K6 merged: raw + conv3 radius aggregation ------------------
__global__ void k_agg(const float* __restrict__ pts, const float* __restrict__ kp,
                      const float* __restrict__ fraw,
                      const float* __restrict__ conv3, const float* __restrict__ gc3,
                      float* __restrict__ feats,
                      float* __restrict__ cntR, float* __restrict__ cntC) {
    __shared__ float sp[2560];
    int bid0 = blockIdx.x;
    int t = threadIdx.x;
    if (bid0 < BN_ * 128) {
        // ---- raw aggregation ----
        int bid = bid0;
        int b = bid >> 7, kb = (bid >> 4) & 7, s = bid & 15;
        int kk = kb * 256 + t, row = b * KP + kk;
        float kx = kp[row * 3], ky = kp[row * 3 + 1], kz = kp[row * 3 + 2];
        float acc[32];
#pragma unroll
        for (int c = 0; c < 32; ++c) acc[c] = 0.f;
        float cnt = 0.f;
        const float R2 = 0.8f * 0.8f;
        for (int tile = 0; tile < 2; ++tile) {
            int nbase = s * 1024 + tile * 512;
            const float* src = pts + (size_t)(b * NPT + nbase) * 5;
            for (int i = t; i < 2560; i += 256) sp[i] = src[i];
            __syncthreads();
            for (int j = 0; j < 512; ++j) {
                float dx = kx - sp[j * 5], dy = ky - sp[j * 5 + 1], dz = kz - sp[j * 5 + 2];
                float d2 = fmaf(dx, dx, fmaf(dy, dy, dz * dz));
                if (d2 < R2) {
                    cnt += 1.f;
                    const float* fp = fraw + (size_t)(b * NPT + nbase + j) * 32;
#pragma unroll
                    for (int c = 0; c < 32; ++c) acc[c] += fp[c];
                }
            }
            __syncthreads();
        }
        float* dst = feats + (size_t)row * 352 + 256;
#pragma unroll
        for (int c = 0; c < 32; ++c) if (acc[c] != 0.f) atomicAdd(dst + c, acc[c]);
        if (cnt != 0.f) atomicAdd(cntR + row, cnt);
    } else {
        // ---- conv3 aggregation ----
        int bid = bid0 - BN_ * 128;
        int b = bid >> 7, kb = (bid >> 4) & 7, s = bid & 15;
        int kk = kb * 256 + t, row = b * KP + kk;
        float kx = kp[row * 3], ky = kp[row * 3 + 1], kz = kp[row * 3 + 2];
        float acc[64];
#pragma unroll
        for (int c = 0; c < 64; ++c) acc[c] = 0.f;
        float cnt = 0.f;
        const float R2 = 1.6f * 1.6f;
        for (int tile = 0; tile < 2; ++tile) {
            int nbase = s * 512 + tile * 256;
            const float* src = conv3 + (size_t)(b * MPT + nbase + t) * 67;
            sp[t * 3] = src[0]; sp[t * 3 + 1] = src[1]; sp[t * 3 + 2] = src[2];
            __syncthreads();
            for (int j = 0; j < 256; ++j) {
                float dx = kx - sp[j * 3], dy = ky - sp[j * 3 + 1], dz = kz - sp[j * 3 + 2];
                float d2 = fmaf(dx, dx, fmaf(dy, dy, dz * dz));
                if (d2 < R2) {
                    cnt += 1.f;
                    const float* gp = gc3 + (size_t)(b * MPT + nbase + j) * 64;
#pragma unroll
                    for (int c = 0; c < 64; ++c) acc[c] += gp[c];
                }
            }
            __syncthreads();
        }
        float* dst = feats + (size_t)row * 352 + 288;
#pragma unroll
        for (int c = 0; c < 64; ++c) if (acc[c] != 0.f) atomicAdd(dst + c, acc[c]);
        if (cnt != 0.f) atomicAdd(cntC + row, cnt);
    }
}

// ---------------- K7: fuse GEMM + BN + ReLU (+ fused bilinear BEV) --------------
__global__ void k_fuse(const float* __restrict__ feats, const float* __restrict__ cntR,
                       const float* __restrict__ cntC, const float* __restrict__ Wf,
                       const float* __restrict__ gma, const float* __restrict__ bta,
                       const float* __restrict__ mean, const float* __restrict__ var,
                       const float* __restrict__ sf, const float* __restrict__ sfT,
                       int useT, const float* __restrict__ kp,
                       float* __restrict__ out) {
    __shared__ float a[2][352];
    int r0 = blockIdx.x * 2;
    int t = threadIdx.x;
    for (int i = t; i < 704; i += 256) {
        int rr = i >= 352 ? 1 : 0;
        int k = i - rr * 352;
        int row = r0 + rr;
        float v;
        if (k < 256) {
            const float* kpr = kp + (size_t)row * 3;
            float x = kpr[0], y = kpr[1];
            float xi = ((x - (-75.2f)) / 0.1f) / 8.0f;
            float yi = ((y - (-75.2f)) / 0.1f) / 8.0f;
            int x0 = (int)floorf(xi); x0 = min(max(x0, 0), 187);
            int x1 = min(max(x0 + 1, 0), 187);
            int y0 = (int)floorf(yi); y0 = min(max(y0, 0), 187);
            int y1 = min(max(y0 + 1, 0), 187);
            float xf0 = (float)x0, xf1 = (float)x1, yf0 = (float)y0, yf1 = (float)y1;
            float wa = (xf1 - xi) * (yf1 - yi), wb = (xf1 - xi) * (yi - yf0);
            float wc = (xi - xf0) * (yf1 - yi), wd = (xi - xf0) * (yi - yf0);
            int bb = row >> 11;
            float Ia, Ib, Ic, Id;
            if (useT) {
                const float* bt = sfT + (size_t)bb * NPOS * 256 + k;
                Ia = bt[(size_t)(y0 * 188 + x0) * 256];
                Ib = bt[(size_t)(y1 * 188 + x0) * 256];
                Ic = bt[(size_t)(y0 * 188 + x1) * 256];
                Id = bt[(size_t)(y1 * 188 + x1) * 256];
            } else {
                const float* plane = sf + (size_t)(bb * 256 + k) * NPOS;
                Ia = plane[y0 * 188 + x0]; Ib = plane[y1 * 188 + x0];
                Ic = plane[y0 * 188 + x1]; Id = plane[y1 * 188 + x1];
            }
            v = Ia * wa + Ib * wb + Ic * wc + Id * wd;
        } else {
            v = feats[(size_t)row * 352 + k];
            float cn = (k < 288) ? cntR[row] : cntC[row];
            v = v / fmaxf(cn, 1.0f);
        }
        a[rr][k] = v;
    }
    __syncthreads();
    int r = t >> 7, c = t & 127;
    float s = 0.f;
#pragma unroll 4
    for (int k = 0; k < 352; ++k) s = fmaf(a[r][k], Wf[k * 128 + c], s);
    s = (s - mean[c]) * (1.0f / sqrtf(var[c] + 1e-5f)) * gma[c] + bta[c];
    out[(size_t)(r0 + r) * 128 + c] = fmaxf(s, 0.f);
}

// ---------------- launch ----------------
extern "C" void kernel_launch(void* const* d_in, const int* in_sizes, int n_in,
                              void* d_out, int out_size, void* d_ws, size_t ws_size,
                              hipStream_t stream) {
    const float* pts   = (const float*)d_in[0];
    const float* bbox  = (const float*)d_in[1];
    const float* sf    = (const float*)d_in[2];
    const float* conv3 = (const float*)d_in[3];
    const float* Wraw  = (const float*)d_in[4];
    const float* braw  = (const float*)d_in[5];
    const float* Wc3   = (const float*)d_in[6];
    const float* bc3   = (const float*)d_in[7];
    const float* Wf    = (const float*)d_in[8];
    const float* gma   = (const float*)d_in[9];
    const float* bta   = (const float*)d_in[10];
    const float* mean  = (const float*)d_in[11];
    const float* var   = (const float*)d_in[12];

    float* wsf   = (float*)d_ws;
    float* feats = wsf;
    float* cntR  = wsf + CNTR_OFF;
    float* cntC  = wsf + CNTC_OFF;
    float* fraw  = wsf + FRAW_OFF;
    float* gc3   = wsf + GC3_OFF;
    unsigned char* flags = (unsigned char*)(wsf + FLAGS_F_OFF);
    float* pxw   = wsf + PX_OFF;
    float* pyw   = wsf + PY_OFF;
    float* pzw   = wsf + PZ_OFF;
    float* sfT   = wsf + SFT_OFF;

    int useT = (ws_size >= (size_t)(SFT_OFF + SFT_LEN) * sizeof(float)) ? 1 : 0;
    int nblocks = useT ? TOTAL_BLOCKS : BASE_BLOCKS;

    float* outp  = (float*)d_out;
    float* kpOut = outp + OUT_KP_OFF;

    k_flags<<<BN_ * 64, 256, 0, stream>>>(pts, bbox, flags);
    k_fps<<<nblocks, 512, 0, stream>>>(pts, flags, pxw, pyw, pzw, kpOut,
                                       conv3, Wc3, bc3, gc3, wsf,
                                       Wraw, braw, fraw, sf, sfT);
    k_agg<<<BN_ * 256, 256, 0, stream>>>(pts, kpOut, fraw, conv3, gc3,
                                         feats, cntR, cntC);
    k_fuse<<<2048, 256, 0, stream>>>(feats, cntR, cntC, Wf, gma, bta, mean, var,
                                     sf, sfT, useT, kpOut, outp);
}

// Round 16
// 1611.099 us; speedup vs baseline: 1.0179x; 1.0179x over previous
//
#include <hip/hip_runtime.h>
#include <stdint.h>

#define BN_ 2
#define NPT 16384
#define MPT 8192
#define NROI 128
#define KP 2048

typedef unsigned long long u64;
typedef unsigned u32;
typedef float v2f __attribute__((ext_vector_type(2)));

// ---- workspace layout (float offsets) ----
#define FEATS_LEN (4096*352)
#define CNTR_OFF  (FEATS_LEN)
#define CNTC_OFF  (CNTR_OFF + 4096)
#define FRAW_OFF  (CNTC_OFF + 4096)
#define FRAW_LEN  (BN_*NPT*32)
#define GC3_OFF   (FRAW_OFF + FRAW_LEN)
#define GC3_LEN   (BN_*MPT*64)
#define FLAGS_F_OFF (GC3_OFF + GC3_LEN)      // flags (bytes) at this float offset
#define PX_OFF    (FLAGS_F_OFF + (BN_*NPT)/4) // SoA compacted coords (fallback)
#define PY_OFF    (PX_OFF + BN_*NPT)
#define PZ_OFF    (PY_OFF + BN_*NPT)
#define SFT_OFF   (PZ_OFF + BN_*NPT)         // channel-last BEV (optional, ws-size gated)
#define NPOS      (188*188)                  // 35344
#define SFT_LEN   (BN_*NPOS*256)
#define OUT_KP_OFF (4096*128)                // keypoints region inside d_out

// fused-dispatch block roles for k_fps
#define FPS_BLOCKS  2
#define GC3_BLOCKS  2048                      // 8 rows x 512thr each
#define ZERO_BLOCKS 177                       // (FEATS_LEN+8192)/4 f4 = 362496 = 177*512*4
#define PTILES      553                       // ceil(35344/64)
#define SFT_BLOCKS  (BN_*4*PTILES)            // 4 k-tiles x 553 pos-tiles per batch
#define BASE_BLOCKS (FPS_BLOCKS + GC3_BLOCKS + ZERO_BLOCKS)
#define TOTAL_BLOCKS (BASE_BLOCKS + SFT_BLOCKS)

// ---------------- helpers ----------------
template <int CTRL>
__device__ __forceinline__ u32 dppmov(u32 v) {
    return (u32)__builtin_amdgcn_update_dpp((int)v, (int)v, CTRL, 0xF, 0xF, false);
}
// Wave64 u32 max via DPP; result broadcast via readlane(63).
__device__ __forceinline__ u32 wave_umax32_dpp(u32 v) {
#define STG(C) { u32 o = dppmov<C>(v); v = (o > v) ? o : v; }
    STG(0x111) STG(0x112) STG(0x114) STG(0x118) STG(0x142) STG(0x143)
#undef STG
    return (u32)__builtin_amdgcn_readlane((int)v, 63);
}

// packed f32 ops (VOP3P) — exact IEEE per half, no contraction possible.
__device__ __forceinline__ v2f pk_add(v2f a, v2f b) {
    v2f r; asm("v_pk_add_f32 %0, %1, %2" : "=v"(r) : "v"(a), "v"(b)); return r;
}
__device__ __forceinline__ v2f pk_mul(v2f a, v2f b) {
    v2f r; asm("v_pk_mul_f32 %0, %1, %2" : "=v"(r) : "v"(a), "v"(b)); return r;
}

// ---------------- K1: ROI validity flags + fused raw-point MLP ----------------
__global__ void k_flags(const float* __restrict__ pts, const float* __restrict__ bbox,
                        unsigned char* __restrict__ flags,
                        const float* __restrict__ Wr, const float* __restrict__ br,
                        float* __restrict__ fraw) {
#pragma clang fp contract(off)
    __shared__ float rx[NROI], ry[NROI], rz[NROI], rt[NROI];
    __shared__ float w0[32], w1[32], bs[32];
    int b = blockIdx.x >> 6;
    int t = threadIdx.x;
    if (t < NROI) {
        const float* rr = bbox + (size_t)(b * NROI + t) * 7;
        rx[t] = rr[0]; ry[t] = rr[1]; rz[t] = rr[2];
        float hx = rr[3] * 0.5f, hy = rr[4] * 0.5f, hz = rr[5] * 0.5f;
        rt[t] = sqrtf(((hx * hx) + (hy * hy)) + (hz * hz)) + 2.4f;
    }
    if (t >= 224) { int c = t - 224; w0[c] = Wr[c]; w1[c] = Wr[32 + c]; bs[c] = br[c]; }
    __syncthreads();
    int p = (blockIdx.x & 63) * 256 + t;
    int n = b * NPT + p;
    const float* pr = pts + (size_t)n * 5;
    float x = pr[0], y = pr[1], z = pr[2];
    float mind = 3.4e38f, th = 0.f;
    for (int r = 0; r < NROI; ++r) {
        float dx = x - rx[r], dy = y - ry[r], dz = z - rz[r];
        float ds = sqrtf(((dx * dx) + (dy * dy)) + (dz * dz));
        if (ds < mind) { mind = ds; th = rt[r]; }   // strict < : first-min == np.argmin
    }
    flags[n] = (mind < th) ? 1 : 0;
    float f3 = pr[3], f4 = pr[4];
    float* fo = fraw + (size_t)n * 32;
#pragma unroll 8
    for (int c = 0; c < 32; ++c)
        fo[c] = fmaxf(fmaf(f3, w0[c], fmaf(f4, w1[c], bs[c])), 0.f);
}

// ---------------- FPS inner loop, LDS-coords variant (R12/R14, verified 1372us) --
// Compacted coords live in LDS (cbuf, float4). Winner fetch is ONE broadcast
// ds_read_b128 instead of 3 L1-thrashing global loads. Tournament via
// triple-buffered single LDS slot + ds_max_u64 from the SINGLE uniform lane
// (lane==0 after ballot/ctz/readlane selection — R13 proved the divergent-
// predicate form is 5.5x slower; keep the uniform single-lane atomic).
// Key = d_bits<<14 | 0x3FFF-gid: exact first-index tie-break (d >= +0.0;
// pads d=+0.0 lose since pad gid >= V). Winner sequence bit-exact.
template <int NS>
__device__ __forceinline__ void fps_loop_l(
    int t, int lane, int w, int V,
    const float4* cbuf,               // LDS compacted coords
    u64* rbuf,                        // LDS, 3 rotating winner slots
    float* kbuf,                      // LDS, KP*3
    float* __restrict__ kout) {
#pragma clang fp contract(off)
    constexpr int NP = NS / 2;
    v2f px[NP], py[NP], pz[NP];
    float d[NS];
    int base = t * NS;                // even (NS even)
#pragma unroll
    for (int m = 0; m < NP; ++m) {
        int id0 = base + 2 * m;
        float4 a = cbuf[id0];
        float4 c = cbuf[id0 + 1];
        bool in0 = id0 < V, in1 = (id0 + 1) < V;
        px[m].x = in0 ? a.x : 1e18f;  px[m].y = in1 ? c.x : 1e18f;
        py[m].x = in0 ? a.y : 1e18f;  py[m].y = in1 ? c.y : 1e18f;
        pz[m].x = in0 ? a.z : 1e18f;  pz[m].y = in1 ? c.z : 1e18f;
        d[2 * m]     = in0 ? 1e10f : 0.0f;   // pad: +0.0 -> loses all ties via gid
        d[2 * m + 1] = in1 ? 1e10f : 0.0f;
    }

    // prime: argmax over initial d (ties -> lowest j, then lowest lane)
    float bestD = -3.4e38f; int bestJ = 0;
#pragma unroll
    for (int j = 0; j < NS; ++j)
        if (d[j] > bestD) { bestD = d[j]; bestJ = j; }
    u32 gid = (u32)(base + bestJ);
    u32 ord = __float_as_uint(bestD);
    u32 maxOrd = wave_umax32_dpp(ord);
    u64 eq = __ballot(ord == maxOrd);
    int L = __builtin_ctzll(eq);
    u32 winGid = (u32)__builtin_amdgcn_readlane((int)gid, L);
    if (lane == 0)
        atomicMax((unsigned long long*)&rbuf[0],
                  ((u64)maxOrd << 14) | (u64)(0x3FFFu - winGid));
    __syncthreads();

    int rd = 0, wr = 1, zr = 2;
    for (int k = 0; k < KP; ++k) {
        // block winner: ONE uniform u64 read, then ONE broadcast b128 read
        u64 win = rbuf[rd];
        u32 wid = 0x3FFFu - ((u32)win & 0x3FFFu);
        float4 wq = cbuf[wid];        // uniform LDS broadcast, no conflict
        float wx = wq.x, wy = wq.y, wz = wq.z;
        if (t == 0) {
            kbuf[k * 3] = wx; kbuf[k * 3 + 1] = wy; kbuf[k * 3 + 2] = wz;
            rbuf[zr] = 0;     // re-zero the idle slot (read finished at k-1)
        }
        v2f wnx; wnx.x = -wx; wnx.y = -wx;
        v2f wny; wny.x = -wy; wny.y = -wy;
        v2f wnz; wnz.x = -wz; wnz.y = -wz;

        // update + sequential local argmax, packed-f32 core (exact: IEEE per
        // half; p + (-w) == p - w exactly)
        bestD = -3.4e38f; bestJ = 0;
#pragma unroll
        for (int m = 0; m < NP; ++m) {
            v2f dx = pk_add(px[m], wnx);
            v2f dy = pk_add(py[m], wny);
            v2f dz = pk_add(pz[m], wnz);
            v2f s  = pk_mul(dx, dx);
            v2f s2 = pk_mul(dy, dy);
            v2f s3 = pk_mul(dz, dz);
            s = pk_add(s, s2);
            s = pk_add(s, s3);
            float dn0 = fminf(d[2 * m], s.x);
            float dn1 = fminf(d[2 * m + 1], s.y);
            d[2 * m] = dn0; d[2 * m + 1] = dn1;
            if (dn0 > bestD) { bestD = dn0; bestJ = 2 * m; }
            if (dn1 > bestD) { bestD = dn1; bestJ = 2 * m + 1; }
        }
        gid = (u32)(base + bestJ);
        ord = __float_as_uint(bestD);
        maxOrd = wave_umax32_dpp(ord);
        eq = __ballot(ord == maxOrd);
        L = __builtin_ctzll(eq);
        winGid = (u32)__builtin_amdgcn_readlane((int)gid, L);
        if (lane == 0)
            atomicMax((unsigned long long*)&rbuf[wr],
                      ((u64)maxOrd << 14) | (u64)(0x3FFFu - winGid));
        __syncthreads();
        int tmp = rd; rd = wr; wr = zr; zr = tmp;
    }
    // flush keypoints LDS -> global (coalesced, once)
    for (int i = t; i < KP * 3; i += 512) kout[i] = kbuf[i];
}

// ---------------- FPS fallback (global SoA), V > 6144 ---------------------------
template <int NS>
__device__ __forceinline__ void fps_loop_g(
    int t, int lane, int w, int V,
    const float* __restrict__ pxg, const float* __restrict__ pyg,
    const float* __restrict__ pzg,
    u64* rbuf, float* kbuf, float* __restrict__ kout) {
#pragma clang fp contract(off)
    constexpr int NP = NS / 2;
    v2f px[NP], py[NP], pz[NP];
    float d[NS];
    int base = t * NS;
#pragma unroll
    for (int m = 0; m < NP; ++m) {
        int id0 = base + 2 * m;
        v2f qx = ((const v2f*)pxg)[base / 2 + m];
        v2f qy = ((const v2f*)pyg)[base / 2 + m];
        v2f qz = ((const v2f*)pzg)[base / 2 + m];
        bool in0 = id0 < V, in1 = (id0 + 1) < V;
        px[m].x = in0 ? qx.x : 1e18f;  px[m].y = in1 ? qx.y : 1e18f;
        py[m].x = in0 ? qy.x : 1e18f;  py[m].y = in1 ? qy.y : 1e18f;
        pz[m].x = in0 ? qz.x : 1e18f;  pz[m].y = in1 ? qz.y : 1e18f;
        d[2 * m]     = in0 ? 1e10f : 0.0f;
        d[2 * m + 1] = in1 ? 1e10f : 0.0f;
    }
    float bestD = -3.4e38f; int bestJ = 0;
#pragma unroll
    for (int j = 0; j < NS; ++j)
        if (d[j] > bestD) { bestD = d[j]; bestJ = j; }
    u32 gid = (u32)(base + bestJ);
    u32 ord = __float_as_uint(bestD);
    u32 maxOrd = wave_umax32_dpp(ord);
    u64 eq = __ballot(ord == maxOrd);
    int L = __builtin_ctzll(eq);
    u32 winGid = (u32)__builtin_amdgcn_readlane((int)gid, L);
    if (lane == 0)
        atomicMax((unsigned long long*)&rbuf[0],
                  ((u64)maxOrd << 14) | (u64)(0x3FFFu - winGid));
    __syncthreads();

    int rd = 0, wr = 1, zr = 2;
    for (int k = 0; k < KP; ++k) {
        u64 win = rbuf[rd];
        u32 wid = 0x3FFFu - ((u32)win & 0x3FFFu);
        float wx = pxg[wid], wy = pyg[wid], wz = pzg[wid];
        if (t == 0) {
            kbuf[k * 3] = wx; kbuf[k * 3 + 1] = wy; kbuf[k * 3 + 2] = wz;
            rbuf[zr] = 0;
        }
        v2f wnx; wnx.x = -wx; wnx.y = -wx;
        v2f wny; wny.x = -wy; wny.y = -wy;
        v2f wnz; wnz.x = -wz; wnz.y = -wz;
        bestD = -3.4e38f; bestJ = 0;
#pragma unroll
        for (int m = 0; m < NP; ++m) {
            v2f dx = pk_add(px[m], wnx);
            v2f dy = pk_add(py[m], wny);
            v2f dz = pk_add(pz[m], wnz);
            v2f s  = pk_mul(dx, dx);
            v2f s2 = pk_mul(dy, dy);
            v2f s3 = pk_mul(dz, dz);
            s = pk_add(s, s2);
            s = pk_add(s, s3);
            float dn0 = fminf(d[2 * m], s.x);
            float dn1 = fminf(d[2 * m + 1], s.y);
            d[2 * m] = dn0; d[2 * m + 1] = dn1;
            if (dn0 > bestD) { bestD = dn0; bestJ = 2 * m; }
            if (dn1 > bestD) { bestD = dn1; bestJ = 2 * m + 1; }
        }
        gid = (u32)(base + bestJ);
        ord = __float_as_uint(bestD);
        maxOrd = wave_umax32_dpp(ord);
        eq = __ballot(ord == maxOrd);
        L = __builtin_ctzll(eq);
        winGid = (u32)__builtin_amdgcn_readlane((int)gid, L);
        if (lane == 0)
            atomicMax((unsigned long long*)&rbuf[wr],
                      ((u64)maxOrd << 14) | (u64)(0x3FFFu - winGid));
        __syncthreads();
        int tmp = rd; rd = wr; wr = zr; zr = tmp;
    }
    for (int i = t; i < KP * 3; i += 512) kout[i] = kbuf[i];
}

// ---------------- K2: fused dispatch — FPS + gc3 + zeroing + sf transpose -------
// LDS layout (122944 B): rbuf 24 | wtot 32 | kbuf 24576 | cbuf 98304.
__global__ void __launch_bounds__(512, 2)
k_fps(const float* __restrict__ pts, const unsigned char* __restrict__ flags,
      float* __restrict__ pxw, float* __restrict__ pyw, float* __restrict__ pzw,
      float* __restrict__ kpOut,
      const float* __restrict__ conv3, const float* __restrict__ Wc,
      const float* __restrict__ bc, float* __restrict__ gc3,
      float* __restrict__ zbase,
      const float* __restrict__ sf, float* __restrict__ sfT) {
#pragma clang fp contract(off)
    __shared__ __align__(16) unsigned char smem[122944];
    int bid = blockIdx.x;
    int t = threadIdx.x;

    if (bid >= BASE_BLOCKS) {
        // ---- sf transpose: 64pos x 64k tile via LDS (conflict-free pad) ----
        int tb = bid - BASE_BLOCKS;            // 0..SFT_BLOCKS-1
        int pt = tb % PTILES;
        int rem = tb / PTILES;                 // 0..(BN_*4-1)
        int kt = rem & 3;
        int bb = rem >> 2;
        int pos0 = pt * 64;
        int k0 = kt * 64;
        float* lds = (float*)smem;             // [64][65]
        int g = t >> 6, l = t & 63;
        const float* src = sf + ((size_t)(bb * 256 + k0) * NPOS) + pos0;
#pragma unroll
        for (int i = 0; i < 8; ++i) {
            int kl = g + 8 * i;
            float v = (pos0 + l < NPOS) ? src[(size_t)kl * NPOS + l] : 0.f;
            lds[kl * 65 + l] = v;
        }
        __syncthreads();
        float* dst = sfT + (size_t)bb * NPOS * 256;
#pragma unroll
        for (int i = 0; i < 8; ++i) {
            int pl = g + 8 * i;
            int pos = pos0 + pl;
            if (pos < NPOS)
                dst[(size_t)pos * 256 + k0 + l] = lds[l * 65 + pl];
        }
        return;
    }
    if (bid >= FPS_BLOCKS + GC3_BLOCKS) {
        // ---- zero feats + counters: 4 float4 per thread, exact coverage ----
        float4* z4 = (float4*)zbase;
        int idx = (bid - FPS_BLOCKS - GC3_BLOCKS) * 512 + t;
        const int STRIDE = ZERO_BLOCKS * 512;
#pragma unroll
        for (int k = 0; k < 4; ++k)
            z4[idx + k * STRIDE] = make_float4(0.f, 0.f, 0.f, 0.f);
        return;
    }
    if (bid >= FPS_BLOCKS) {
        // ---- gc3 MLP: 8 rows per block, bit-identical to former k_gc3 ----
        float* w = (float*)smem;                       // 16KB
        float (*rf)[64] = (float(*)[64])(smem + 16384); // 2KB
        for (int i = t; i < 4096; i += 512) w[i] = Wc[i];
        int r = (bid - FPS_BLOCKS) * 8 + (t >> 6);
        int c = t & 63;
        rf[t >> 6][c] = conv3[(size_t)r * 67 + 3 + c];
        __syncthreads();
        float s = bc[c];
#pragma unroll 8
        for (int k = 0; k < 64; ++k) s = fmaf(rf[t >> 6][k], w[k * 64 + c], s);
        gc3[(size_t)r * 64 + c] = fmaxf(s, 0.f);
        return;
    }

    // ---- FPS path (blocks 0..1), 512 threads = 8 waves = 2 waves/SIMD ----
    u64* rbuf    = (u64*)smem;                         // 24 B (3 slots)
    int* wtot    = (int*)(smem + 32);                  // 32 B
    float* kbuf  = (float*)(smem + 64);                // 24576 B -> ends 24640
    float4* cbuf = (float4*)(smem + 24640);            // 98304 B -> ends 122944

    int b = bid;
    int lane = t & 63, w = t >> 6;
    int chunk = t * 32;   // 32 contiguous input points per thread
    const float* pbase = pts + (size_t)b * NPT * 5;
    const unsigned char* fbase = flags + b * NPT;

    if (t < 3) rbuf[t] = 0;   // zero winner slots (visible after barrier below)

    // pass 1: count valid in my chunk
    int cnt = 0;
    for (int j = 0; j < 32; ++j) cnt += fbase[chunk + j] ? 1 : 0;
    int incl = cnt;
#pragma unroll
    for (int off = 1; off < 64; off <<= 1) {
        int v = __shfl_up(incl, off, 64);
        if (lane >= off) incl += v;
    }
    if (lane == 63) wtot[w] = incl;
    __syncthreads();
    int waveBase = 0, V = 0;
    for (int i = 0; i < 8; ++i) { int wv = wtot[i]; V += wv; if (i < w) waveBase += wv; }
    int pos = waveBase + incl - cnt;

    float* kout = kpOut + (size_t)b * KP * 3;
    if (V == 0) {      // degenerate: reference picks index 0 every step
        if (t == 0)
            for (int k = 0; k < KP; ++k) {
                kout[k * 3] = pbase[0]; kout[k * 3 + 1] = pbase[1]; kout[k * 3 + 2] = pbase[2];
            }
        return;
    }

    if (V <= 6144) {
        // pass 2: stable scatter of compacted coords into LDS cbuf
        for (int j = 0; j < 32; ++j) {
            if (fbase[chunk + j]) {
                const float* pr = pbase + (size_t)(chunk + j) * 5;
                cbuf[pos] = make_float4(pr[0], pr[1], pr[2], 0.f);
                ++pos;
            }
        }
        __syncthreads();   // scatter + rbuf zeroing visible to block
        int jm = (V + 511) >> 9;
        if (jm <= 10)      fps_loop_l<10>(t, lane, w, V, cbuf, rbuf, kbuf, kout);
        else               fps_loop_l<12>(t, lane, w, V, cbuf, rbuf, kbuf, kout);
    } else {
        // fallback: scatter to global SoA ws
        float* pxg = pxw + (size_t)b * NPT;
        float* pyg = pyw + (size_t)b * NPT;
        float* pzg = pzw + (size_t)b * NPT;
        int pp = pos;
        for (int j = 0; j < 32; ++j) {
            if (fbase[chunk + j]) {
                const float* pr = pbase + (size_t)(chunk + j) * 5;
                pxg[pp] = pr[0]; pyg[pp] = pr[1]; pzg[pp] = pr[2];
                ++pp;
            }
        }
        __syncthreads();
        int jm = (V + 511) >> 9;
        if (jm <= 14)      fps_loop_g<14>(t, lane, w, V, pxg, pyg, pzg, rbuf, kbuf, kout);
        else if (jm <= 16) fps_loop_g<16>(t, lane, w, V, pxg, pyg, pzg, rbuf, kbuf, kout);
        else if (jm <= 24) fps_loop_g<24>(t, lane, w, V, pxg, pyg, pzg, rbuf, kbuf, kout);
        else               fps_loop_g<32>(t, lane, w, V, pxg, pyg, pzg, rbuf, kbuf, kout);
    }
}

// ---------------- K5+K6 merged: raw + conv3 radius aggregation ------------------
__global__ void k_agg(const float* __restrict__ pts, const float* __restrict__ kp,
                      const float* __restrict__ fraw,
                      const float* __restrict__ conv3, const float* __restrict__ gc3,
                      float* __restrict__ feats,
                      float* __restrict__ cntR, float* __restrict__ cntC) {
    __shared__ float sp[2560];
    int bid0 = blockIdx.x;
    int t = threadIdx.x;
    if (bid0 < BN_ * 128) {
        // ---- raw aggregation ----
        int bid = bid0;
        int b = bid >> 7, kb = (bid >> 4) & 7, s = bid & 15;
        int kk = kb * 256 + t, row = b * KP + kk;
        float kx = kp[row * 3], ky = kp[row * 3 + 1], kz = kp[row * 3 + 2];
        float acc[32];
#pragma unroll
        for (int c = 0; c < 32; ++c) acc[c] = 0.f;
        float cnt = 0.f;
        const float R2 = 0.8f * 0.8f;
        for (int tile = 0; tile < 2; ++tile) {
            int nbase = s * 1024 + tile * 512;
            const float* src = pts + (size_t)(b * NPT + nbase) * 5;
            for (int i = t; i < 2560; i += 256) sp[i] = src[i];
            __syncthreads();
            for (int j = 0; j < 512; ++j) {
                float dx = kx - sp[j * 5], dy = ky - sp[j * 5 + 1], dz = kz - sp[j * 5 + 2];
                float d2 = fmaf(dx, dx, fmaf(dy, dy, dz * dz));
                if (d2 < R2) {
                    cnt += 1.f;
                    const float* fp = fraw + (size_t)(b * NPT + nbase + j) * 32;
#pragma unroll
                    for (int c = 0; c < 32; ++c) acc[c] += fp[c];
                }
            }
            __syncthreads();
        }
        float* dst = feats + (size_t)row * 352 + 256;
#pragma unroll
        for (int c = 0; c < 32; ++c) if (acc[c] != 0.f) atomicAdd(dst + c, acc[c]);
        if (cnt != 0.f) atomicAdd(cntR + row, cnt);
    } else {
        // ---- conv3 aggregation ----
        int bid = bid0 - BN_ * 128;
        int b = bid >> 7, kb = (bid >> 4) & 7, s = bid & 15;
        int kk = kb * 256 + t, row = b * KP + kk;
        float kx = kp[row * 3], ky = kp[row * 3 + 1], kz = kp[row * 3 + 2];
        float acc[64];
#pragma unroll
        for (int c = 0; c < 64; ++c) acc[c] = 0.f;
        float cnt = 0.f;
        const float R2 = 1.6f * 1.6f;
        for (int tile = 0; tile < 2; ++tile) {
            int nbase = s * 512 + tile * 256;
            const float* src = conv3 + (size_t)(b * MPT + nbase + t) * 67;
            sp[t * 3] = src[0]; sp[t * 3 + 1] = src[1]; sp[t * 3 + 2] = src[2];
            __syncthreads();
            for (int j = 0; j < 256; ++j) {
                float dx = kx - sp[j * 3], dy = ky - sp[j * 3 + 1], dz = kz - sp[j * 3 + 2];
                float d2 = fmaf(dx, dx, fmaf(dy, dy, dz * dz));
                if (d2 < R2) {
                    cnt += 1.f;
                    const float* gp = gc3 + (size_t)(b * MPT + nbase + j) * 64;
#pragma unroll
                    for (int c = 0; c < 64; ++c) acc[c] += gp[c];
                }
            }
            __syncthreads();
        }
        float* dst = feats + (size_t)row * 352 + 288;
#pragma unroll
        for (int c = 0; c < 64; ++c) if (acc[c] != 0.f) atomicAdd(dst + c, acc[c]);
        if (cnt != 0.f) atomicAdd(cntC + row, cnt);
    }
}

// ---------------- K7: fuse GEMM + BN + ReLU (+ fused bilinear BEV) --------------
__global__ void k_fuse(const float* __restrict__ feats, const float* __restrict__ cntR,
                       const float* __restrict__ cntC, const float* __restrict__ Wf,
                       const float* __restrict__ gma, const float* __restrict__ bta,
                       const float* __restrict__ mean, const float* __restrict__ var,
                       const float* __restrict__ sf, const float* __restrict__ sfT,
                       int useT, const float* __restrict__ kp,
                       float* __restrict__ out) {
    __shared__ float a[2][352];
    int r0 = blockIdx.x * 2;
    int t = threadIdx.x;
    for (int i = t; i < 704; i += 256) {
        int rr = i >= 352 ? 1 : 0;
        int k = i - rr * 352;
        int row = r0 + rr;
        float v;
        if (k < 256) {
            const float* kpr = kp + (size_t)row * 3;
            float x = kpr[0], y = kpr[1];
            float xi = ((x - (-75.2f)) / 0.1f) / 8.0f;
            float yi = ((y - (-75.2f)) / 0.1f) / 8.0f;
            int x0 = (int)floorf(xi); x0 = min(max(x0, 0), 187);
            int x1 = min(max(x0 + 1, 0), 187);
            int y0 = (int)floorf(yi); y0 = min(max(y0, 0), 187);
            int y1 = min(max(y0 + 1, 0), 187);
            float xf0 = (float)x0, xf1 = (float)x1, yf0 = (float)y0, yf1 = (float)y1;
            float wa = (xf1 - xi) * (yf1 - yi), wb = (xf1 - xi) * (yi - yf0);
            float wc = (xi - xf0) * (yf1 - yi), wd = (xi - xf0) * (yi - yf0);
            int bb = row >> 11;
            float Ia, Ib, Ic, Id;
            if (useT) {
                const float* bt = sfT + (size_t)bb * NPOS * 256 + k;
                Ia = bt[(size_t)(y0 * 188 + x0) * 256];
                Ib = bt[(size_t)(y1 * 188 + x0) * 256];
                Ic = bt[(size_t)(y0 * 188 + x1) * 256];
                Id = bt[(size_t)(y1 * 188 + x1) * 256];
            } else {
                const float* plane = sf + (size_t)(bb * 256 + k) * NPOS;
                Ia = plane[y0 * 188 + x0]; Ib = plane[y1 * 188 + x0];
                Ic = plane[y0 * 188 + x1]; Id = plane[y1 * 188 + x1];
            }
            v = Ia * wa + Ib * wb + Ic * wc + Id * wd;
        } else {
            v = feats[(size_t)row * 352 + k];
            float cn = (k < 288) ? cntR[row] : cntC[row];
            v = v / fmaxf(cn, 1.0f);
        }
        a[rr][k] = v;
    }
    __syncthreads();
    int r = t >> 7, c = t & 127;
    float s = 0.f;
#pragma unroll 4
    for (int k = 0; k < 352; ++k) s = fmaf(a[r][k], Wf[k * 128 + c], s);
    s = (s - mean[c]) * (1.0f / sqrtf(var[c] + 1e-5f)) * gma[c] + bta[c];
    out[(size_t)(r0 + r) * 128 + c] = fmaxf(s, 0.f);
}

// ---------------- launch ----------------
extern "C" void kernel_launch(void* const* d_in, const int* in_sizes, int n_in,
                              void* d_out, int out_size, void* d_ws, size_t ws_size,
                              hipStream_t stream) {
    const float* pts   = (const float*)d_in[0];
    const float* bbox  = (const float*)d_in[1];
    const float* sf    = (const float*)d_in[2];
    const float* conv3 = (const float*)d_in[3];
    const float* Wraw  = (const float*)d_in[4];
    const float* braw  = (const float*)d_in[5];
    const float* Wc3   = (const float*)d_in[6];
    const float* bc3   = (const float*)d_in[7];
    const float* Wf    = (const float*)d_in[8];
    const float* gma   = (const float*)d_in[9];
    const float* bta   = (const float*)d_in[10];
    const float* mean  = (const float*)d_in[11];
    const float* var   = (const float*)d_in[12];

    float* wsf   = (float*)d_ws;
    float* feats = wsf;
    float* cntR  = wsf + CNTR_OFF;
    float* cntC  = wsf + CNTC_OFF;
    float* fraw  = wsf + FRAW_OFF;
    float* gc3   = wsf + GC3_OFF;
    unsigned char* flags = (unsigned char*)(wsf + FLAGS_F_OFF);
    float* pxw   = wsf + PX_OFF;
    float* pyw   = wsf + PY_OFF;
    float* pzw   = wsf + PZ_OFF;
    float* sfT   = wsf + SFT_OFF;

    int useT = (ws_size >= (size_t)(SFT_OFF + SFT_LEN) * sizeof(float)) ? 1 : 0;
    int nblocks = useT ? TOTAL_BLOCKS : BASE_BLOCKS;

    float* outp  = (float*)d_out;
    float* kpOut = outp + OUT_KP_OFF;

    k_flags<<<BN_ * 64, 256, 0, stream>>>(pts, bbox, flags, Wraw, braw, fraw);
    k_fps<<<nblocks, 512, 0, stream>>>(pts, flags, pxw, pyw, pzw, kpOut,
                                       conv3, Wc3, bc3, gc3, wsf, sf, sfT);
    k_agg<<<BN_ * 256, 256, 0, stream>>>(pts, kpOut, fraw, conv3, gc3,
                                         feats, cntR, cntC);
    k_fuse<<<2048, 256, 0, stream>>>(feats, cntR, cntC, Wf, gma, bta, mean, var,
                                     sf, sfT, useT, kpOut, outp);
}